// Round 2
// baseline (649.309 us; speedup 1.0000x reference)
//
#include <hip/hip_runtime.h>

// GatherLayer: out[b, :] = full_output[b, idx[b]*512 : (idx[b]+1)*512]
// BATCH=16384, OUTPUT_DIM=512, NB_ACTIONS=18.
// Pure memory-bound gather-copy: 32 MB read + 32 MB write, no reuse, no
// compute -> roofline ~10 us at 6.3 TB/s achievable HBM BW.
//
// Layout: ONE WAVE PER ROW. Each 64-lane wave copies one 512-float (2 KB)
// row: the action index is wave-uniform, so it is read once per wave via a
// scalar load (readfirstlane), and each lane moves 2 independent float4s
// (lane and lane+64) -> 2 KB contiguous read + 2 KB contiguous write per
// wave, perfectly coalesced on both sides.

#define BATCH 16384
#define OUTPUT_DIM 512
#define NB_ACTIONS 18
#define ROW_STRIDE_V4 (OUTPUT_DIM * NB_ACTIONS / 4)  // 2304 float4 per input row
#define OUT_ROW_V4    (OUTPUT_DIM / 4)               // 128 float4 per output row

__global__ __launch_bounds__(256) void gather_kernel(
    const float4* __restrict__ in,   // [BATCH, ROW_STRIDE_V4]
    const int*    __restrict__ idx,  // [BATCH]
    float4*       __restrict__ out)  // [BATCH, OUT_ROW_V4]
{
    const int gtid = blockIdx.x * blockDim.x + threadIdx.x;
    const int b    = gtid >> 6;          // global wave id == row id (exact grid)
    const int lane = threadIdx.x & 63;

    // idx[b] is wave-uniform: force a single scalar load per wave.
    const int a = __builtin_amdgcn_readfirstlane(idx[b]);

    const float4* __restrict__ src = in  + b * ROW_STRIDE_V4 + a * OUT_ROW_V4;
    float4*       __restrict__ dst = out + b * OUT_ROW_V4;

    // Two independent 16B loads in flight per lane (MLP), then two stores.
    float4 v0 = src[lane];
    float4 v1 = src[lane + 64];
    dst[lane]      = v0;
    dst[lane + 64] = v1;
}

extern "C" void kernel_launch(void* const* d_in, const int* in_sizes, int n_in,
                              void* d_out, int out_size, void* d_ws, size_t ws_size,
                              hipStream_t stream) {
    const float4* in  = (const float4*)d_in[0];
    const int*    idx = (const int*)d_in[1];
    float4*       out = (float4*)d_out;

    // One wave per row: 16384 waves = 1,048,576 threads = 4096 blocks of 256.
    const int block = 256;
    const int grid  = BATCH * 64 / block;   // 4096
    gather_kernel<<<grid, block, 0, stream>>>(in, idx, out);
}